// Round 5
// baseline (107.007 us; speedup 1.0000x reference)
//
#include <hip/hip_runtime.h>

#define KSZ   121
#define KMEAN 60
#define IMW   512
#define IMH   512
#define NPLANES 24            // 8 * 3
#define NROWS (NPLANES * IMH) // 12288 independent image rows
#define TK    640             // padded k-extent of tmp^T (64 | 512 | 64)
#define TPAD  64

typedef float    f32x4 __attribute__((ext_vector_type(4)));
typedef _Float16 f16x8 __attribute__((ext_vector_type(8)));

// ---------------------------------------------------------------------------
// ws layout (bytes):
//   [    0,  512)  taps w[0..120] fp32 (pad to 128 with 0)
//   [  512, 2560)  L[512] fp32   (float idx 128..640)
//   [ 2560, 4608)  R[512] fp32   (float idx 640..1152)
//   [ 4608,14848)  10 MFMA weight-band tables, fp16, fragment order:
//                    T[tt][lane][j], tt = tau+1, tau in [-1,8]
//                    value = w[16*tau + kk - ci - 4], kk = 8*(lane>>4)+j,
//                    ci = lane&15; 0 outside [0,120].
//   [16384, ... )  fp16 tmp^T: [plane][col][TK], k stored at entry k+64;
//                  entries [0,64) and [576,640) are ZEROED pads.
//
// Banded-matmul identity (w-idx = 16(2s-n)+kk-i-4, tau = 2s-n), both passes:
//   h-pass (TRANSPOSED this round): th^T[c,r]: A = table (i=out-col c),
//          B = x-row fragments (j=image row r, slots k = image cols).
//   v-pass: out[r,c]: A = table (i=out-row r), B = tmpT (j=out-col c,
//          slots k contiguous in tmpT).
// The A=table/B=data configuration is exactly what rounds 2/4 proved.
// ---------------------------------------------------------------------------
__global__ __launch_bounds__(128) void weights_kernel(const float* __restrict__ sigma,
                                                      float* __restrict__ ws) {
    __shared__ float w[121];
    __shared__ float P[121];
    int t = threadIdx.x;
    float s = sigma[0] * 8.0f + 16.0f;
    float ninv = -1.0f / (2.0f * s * s);
    if (t < 121) { float d = (float)(t - KMEAN); w[t] = __expf(d * d * ninv); }
    __syncthreads();
    if (t == 0) {
        float sum = 0.f;
        for (int i = 0; i < 121; ++i) sum += w[i];
        float inv = 1.f / sum, run = 0.f;
        for (int i = 0; i < 121; ++i) { float wi = w[i] * inv; w[i] = wi; run += wi; P[i] = run; }
    }
    __syncthreads();
    ws[t] = (t < 121) ? w[t] : 0.f;                       // taps, 121..127 = 0
    #pragma unroll
    for (int j = 0; j < 4; ++j) {
        int o = t * 4 + j;
        ws[128 + o] = (o <= 59)  ? P[59 - o]          : 0.f;   // L
        ws[640 + o] = (o >= 452) ? (1.f - P[571 - o]) : 0.f;   // R
    }
    // MFMA band tables (fp16, fragment order). 10 tables x 512 entries.
    _Float16* tab = (_Float16*)((char*)ws + 4608);
    #pragma unroll
    for (int tt = 0; tt < 10; ++tt) {
        for (int e = t; e < 512; e += 128) {
            int lane = e >> 3, j = e & 7;
            int kk = ((lane >> 4) << 3) + j;   // slot->k convention (shared A/B)
            int ci = lane & 15;
            int wi = 16 * (tt - 1) + kk - ci - 4;
            float v = (wi >= 0 && wi <= 120) ? w[wi] : 0.f;
            tab[tt * 512 + e] = (_Float16)v;
        }
    }
}

// ---------------------------------------------------------------------------
// hblur step body, shape-specialized. ALL loads issued upfront (12 dwordx4
// in flight = 192 B/lane MLP), then cvt+MFMA. No pipeline buffers.
// ---------------------------------------------------------------------------
template<int S0, int S1>
__device__ __forceinline__ void hsteps(const float* __restrict__ xr,
                                       int c0, int g,
                                       const f16x8 (&T)[10],
                                       f32x4 (&acc)[4]) {
    f32x4 u0[6], u1[6];
    #pragma unroll
    for (int s = S0; s < S1; ++s) {
        const int co = c0 - 64 + 32 * s + 8 * g;   // lane's 8 k-slots
        u0[s] = *(const f32x4*)(xr + co);
        u1[s] = *(const f32x4*)(xr + co + 4);
    }
    #pragma unroll
    for (int s = S0; s < S1; ++s) {
        f16x8 B;
        B[0]=(_Float16)u0[s].x; B[1]=(_Float16)u0[s].y;
        B[2]=(_Float16)u0[s].z; B[3]=(_Float16)u0[s].w;
        B[4]=(_Float16)u1[s].x; B[5]=(_Float16)u1[s].y;
        B[6]=(_Float16)u1[s].z; B[7]=(_Float16)u1[s].w;
        #pragma unroll
        for (int n = 0; n < 4; ++n) {
            const int tt = 2 * s - n + 1;          // tau+1, compile-time
            if (tt >= 0 && tt < 10)
                acc[n] = __builtin_amdgcn_mfma_f32_16x16x32_f16(T[tt], B, acc[n], 0, 0, 0);
        }
    }
}

// ---------------------------------------------------------------------------
// Kernel 2: horizontal pass, TRANSPOSED banded f16 MFMA.
//   th[c, r] = sum_k w[k-c+60]*xz[r,k] + x[r,0]*L[c] + x[r,511]*R[c]
// A = band tables (i = out-col c), B = x rows (j = image row r = lane&15,
// slots = image cols, contiguous -> the SAME coalesced f32x4 loads as
// rounds 1-4). D layout: j=ci = image row, i=4g+reg = out-col -> stores land
// k-contiguous across 16 ci-lanes = 32B segments in tmpT (round-2-proven
// store pattern; kills round-4's 1280B-stride 8B scatter).
// Wave = 16 rows x 64 cols; block = 4 waves = 64 rows x 64 cols; 1536 blocks
// = 6144 waves (2x round-4 TLP).
// ---------------------------------------------------------------------------
__global__ __launch_bounds__(256) void hblur_mfma(const float* __restrict__ x,
                                                  const float* __restrict__ ws,
                                                  _Float16* __restrict__ tmpT) {
    const int bid = blockIdx.x;
    const int swz = (bid & 7) * 192 + (bid >> 3);  // 1536 = 8*192, bijective
    const int br = swz >> 3;                 // 0..191 row-block (64 rows)
    const int bc = swz & 7;                  // 0..7   col-tile (64 cols)
    const int tid  = threadIdx.x;
    const int lane = tid & 63;
    const int g    = lane >> 4;
    const int ci   = lane & 15;              // image row within wave tile
    const int wq   = tid >> 6;
    const int R0   = br * 64 + wq * 16;      // wave's first image row
    const int c0   = bc * 64;
    const int plane = br >> 3;               // 8 row-blocks per plane
    const int rp0   = (br & 7) * 64 + wq * 16;   // row-in-plane base

    // preload the 10 band tables (A-operands, wave-uniform)
    const _Float16* __restrict__ tab = (const _Float16*)((const char*)ws + 4608);
    f16x8 T[10];
    #pragma unroll
    for (int tt = 0; tt < 10; ++tt)
        T[tt] = ((const f16x8*)(tab + tt * 512))[lane];

    f32x4 acc[4];
    #pragma unroll
    for (int n = 0; n < 4; ++n)
        acc[n] = (f32x4){0.f, 0.f, 0.f, 0.f};

    const float* __restrict__ xr = x + (size_t)(R0 + ci) * IMW;   // lane's row

    // compile-time shapes: steps with colbase outside [0,512) dropped
    if (c0 == 0)        hsteps<2, 6>(xr, c0, g, T, acc);
    else if (c0 == 448) hsteps<0, 4>(xr, c0, g, T, acc);
    else                hsteps<0, 6>(xr, c0, g, T, acc);

    // replicate-pad corrections (nonzero L/R only in edge col-tiles)
    if (c0 == 0 || c0 == 448) {
        const float* __restrict__ Lf = ws + 128;
        const float* __restrict__ Rf = ws + 640;
        const float x0 = xr[0], xN = xr[IMW - 1];
        #pragma unroll
        for (int n = 0; n < 4; ++n) {
            f32x4 L4 = *(const f32x4*)(Lf + c0 + 16 * n + 4 * g);
            f32x4 R4 = *(const f32x4*)(Rf + c0 + 16 * n + 4 * g);
            #pragma unroll
            for (int r = 0; r < 4; ++r)
                acc[n][r] += x0 * L4[r] + xN * R4[r];
        }
    }

    // store: value (n, reg r) -> tmpT[plane][c0+16n+4g+r][TPAD + rp0 + ci];
    // 16 ci-lanes are consecutive k-entries -> 32B segments per (n,r,g).
    _Float16* __restrict__ tq = tmpT + (size_t)plane * (IMW * TK);
    const int ke = TPAD + rp0 + ci;
    #pragma unroll
    for (int n = 0; n < 4; ++n)
        #pragma unroll
        for (int r = 0; r < 4; ++r)
            tq[(size_t)(c0 + 16 * n + 4 * g + r) * TK + ke] = (_Float16)acc[n][r];

    // zero the k-pads once per (plane, col-tile): first row-block of plane
    if ((br & 7) == 0) {
        const int col  = c0 + (tid >> 2);
        const int part = tid & 3;
        _Float16* __restrict__ pz = tq + (size_t)col * TK
                                       + ((part < 2) ? part * 32 : 576 + (part - 2) * 32);
        const f16x8 z = (f16x8){0, 0, 0, 0, 0, 0, 0, 0};
        #pragma unroll
        for (int i = 0; i < 4; ++i)
            *(f16x8*)(pz + 8 * i) = z;
    }
}

// ---------------------------------------------------------------------------
// Kernel 3: vertical pass, banded f16 MFMA on transposed tmp.
//   out[r,c] = sum_k w[k-r+60]*tmp[k,c] + L[r]*tmp[0,c] + R[r]*tmp[511,c]
// A = band tables (i = out-row). B = tmpT fragments, k contiguous -> one 16B
// f16x8 load per fragment; pads supply the vertical zero-pad. ALL 6 window
// loads issued upfront (96 B/lane MLP). Wave = 64 rows x 16 cols; block =
// 4 waves = 64 rows x 64 cols; 1536 blocks = 6144 waves (2x round-4 TLP).
// ---------------------------------------------------------------------------
__global__ __launch_bounds__(256) void vblur_mfma(const _Float16* __restrict__ tmpT,
                                                  const float* __restrict__ ws,
                                                  float* __restrict__ out) {
    const int bid = blockIdx.x;
    const int swz = (bid & 7) * 192 + (bid >> 3);  // 1536 = 8*192, bijective
    const int rb  = swz >> 3;                      // 0..191: 64-row block
    const int bc  = swz & 7;                       // 0..7: 64-col block
    const int tid  = threadIdx.x;
    const int lane = tid & 63;
    const int wv   = tid >> 6;                     // wave -> 16-col tile
    const int g    = lane >> 4;
    const int ci   = lane & 15;                    // out-col within tile
    const int plane = rb >> 3;
    const int r0p   = (rb & 7) * 64;               // row base within plane
    const int cw    = bc * 64 + wv * 16;

    const _Float16* __restrict__ tq = tmpT + (size_t)plane * (IMW * TK);
    const _Float16* __restrict__ bp = tq + (size_t)(cw + ci) * TK;   // lane col
    float* __restrict__ op = out + (size_t)plane * (IMW * IMH);

    // preload the 10 band tables as A-operands (lane&15 = out-row, slots = k)
    const _Float16* __restrict__ tab = (const _Float16*)((const char*)ws + 4608);
    f16x8 T[10];
    #pragma unroll
    for (int tt = 0; tt < 10; ++tt)
        T[tt] = ((const f16x8*)(tab + tt * 512))[lane];

    // ALL 6 B-fragments upfront: entry r0p+32s+8g in [0, 639], pads give 0.
    f16x8 B[6];
    #pragma unroll
    for (int s = 0; s < 6; ++s)
        B[s] = *(const f16x8*)(bp + r0p + 32 * s + 8 * g);

    f32x4 acc[4];
    #pragma unroll
    for (int n = 0; n < 4; ++n)
        acc[n] = (f32x4){0.f, 0.f, 0.f, 0.f};

    #pragma unroll
    for (int s = 0; s < 6; ++s)
        #pragma unroll
        for (int n = 0; n < 4; ++n) {
            const int tt = 2 * s - n + 1;          // tau+1, compile-time
            if (tt >= 0 && tt < 10)
                acc[n] = __builtin_amdgcn_mfma_f32_16x16x32_f16(T[tt], B[s], acc[n], 0, 0, 0);
        }

    // replicate-pad corrections: tmp rows 0/511 = tmpT entries TPAD/TPAD+511
    if (r0p == 0 || r0p == 448) {
        const float* __restrict__ Lf = ws + 128;
        const float* __restrict__ Rf = ws + 640;
        const float t0 = (float)bp[TPAD];
        const float tN = (float)bp[TPAD + IMH - 1];
        #pragma unroll
        for (int n = 0; n < 4; ++n) {
            f32x4 L4 = *(const f32x4*)(Lf + r0p + 16 * n + 4 * g);
            f32x4 R4 = *(const f32x4*)(Rf + r0p + 16 * n + 4 * g);
            #pragma unroll
            for (int r = 0; r < 4; ++r)
                acc[n][r] += L4[r] * t0 + R4[r] * tN;
        }
    }

    // store fp32: row = r0p+16n+4g+r, col = cw+ci (16 lanes -> 64B segments)
    #pragma unroll
    for (int n = 0; n < 4; ++n)
        #pragma unroll
        for (int r = 0; r < 4; ++r)
            op[(size_t)(r0p + 16 * n + 4 * g + r) * IMW + cw + ci] = acc[n][r];
}

// ---------------------------------------------------------------------------
extern "C" void kernel_launch(void* const* d_in, const int* in_sizes, int n_in,
                              void* d_out, int out_size, void* d_ws, size_t ws_size,
                              hipStream_t stream) {
    const float* x     = (const float*)d_in[0];
    const float* sigma = (const float*)d_in[1];
    float* out = (float*)d_out;

    // ws: taps/L/R fp32 [0,4608) bytes, fp16 band tables [4608,14848),
    // fp16 tmp^T (24 planes x 512 cols x TK entries) at byte 16384.
    float* ws_f = (float*)d_ws;
    _Float16* tmpT = (_Float16*)((char*)d_ws + 16384);

    weights_kernel<<<1, 128, 0, stream>>>(sigma, ws_f);
    hblur_mfma<<<(NROWS / 64) * (IMW / 64), 256, 0, stream>>>(x, ws_f, tmpT);
    vblur_mfma<<<(NROWS / 64) * (IMW / 64), 256, 0, stream>>>(tmpT, ws_f, out);
}